// Round 1
// 503.073 us; speedup vs baseline: 1.0668x; 1.0668x over previous
//
#include <hip/hip_runtime.h>
#include <math.h>

#define NN 50000
#define EE 800000
#define FF 128

constexpr float LN_EPS = 1e-5f;
constexpr int NC = (NN + 255) / 256;   // 196 scan chunks

typedef float  f32x4  __attribute__((ext_vector_type(4)));
typedef short  s16x8  __attribute__((ext_vector_type(8)));
typedef unsigned short u16x4 __attribute__((ext_vector_type(4)));

__device__ __forceinline__ float silu_f(float v) {
    return v / (1.f + __expf(-v));
}

__device__ __forceinline__ unsigned short f2bf(float f) {
    union { float f; unsigned u; } cv; cv.f = f;
    unsigned u = cv.u;
    u += 0x7fffu + ((u >> 16) & 1u);   // round-to-nearest-even
    return (unsigned short)(u >> 16);
}

__device__ __forceinline__ float bf2f(unsigned short u) {
    union { unsigned u; float f; } cv; cv.u = ((unsigned)u) << 16;
    return cv.f;
}

// -------------------- prep: x -> bf16 --------------------
__global__ __launch_bounds__(256) void convert_x_kernel(
    const float* __restrict__ x, unsigned short* __restrict__ xb)
{
    int i = (blockIdx.x * 256 + threadIdx.x) * 8;
    float4 a = *(const float4*)&x[i];
    float4 b = *(const float4*)&x[i + 4];
    s16x8 o;
    o[0] = (short)f2bf(a.x); o[1] = (short)f2bf(a.y);
    o[2] = (short)f2bf(a.z); o[3] = (short)f2bf(a.w);
    o[4] = (short)f2bf(b.x); o[5] = (short)f2bf(b.y);
    o[6] = (short)f2bf(b.z); o[7] = (short)f2bf(b.w);
    *(s16x8*)&xb[i] = o;
}

// -------------------- prep: transpose all weights -> bf16 --------------------
__global__ __launch_bounds__(256) void transpose_w_kernel(
    const float* __restrict__ ew1, const float* __restrict__ ew2,
    const float* __restrict__ nw1, const float* __restrict__ nw2,
    unsigned short* __restrict__ ew1T, unsigned short* __restrict__ ew2T,
    unsigned short* __restrict__ nw1T, unsigned short* __restrict__ nw2T)
{
    int o = blockIdx.x * 256 + threadIdx.x;
    if (o < 32768) {
        int n = o >> 8, k = o & 255;
        ew1T[o] = f2bf(ew1[k * FF + n]);
    } else if (o < 49152) {
        int o2 = o - 32768; int n = o2 >> 7, k = o2 & 127;
        ew2T[o2] = f2bf(ew2[k * FF + n]);
    } else if (o < 65536) {
        int o2 = o - 49152; int n = o2 >> 7, k = o2 & 127;
        nw1T[o2] = f2bf(nw1[k * FF + n]);
    } else {
        int o2 = o - 65536; int n = o2 >> 7, k = o2 & 127;
        nw2T[o2] = f2bf(nw2[k * FF + n]);
    }
}

// -------------------- counting sort by row --------------------
__global__ __launch_bounds__(256) void hist_kernel(
    const int* __restrict__ ei, int* __restrict__ cnt)
{
    int e = blockIdx.x * 256 + threadIdx.x;
    if (e < EE) atomicAdd(&cnt[ei[e]], 1);
}

__global__ __launch_bounds__(256) void chunk_sum_kernel(
    const int* __restrict__ cnt, int* __restrict__ chunkSum)
{
    __shared__ int s[256];
    int t = threadIdx.x;
    int idx = blockIdx.x * 256 + t;
    s[t] = (idx < NN) ? cnt[idx] : 0;
    __syncthreads();
    for (int off = 128; off > 0; off >>= 1) {
        if (t < off) s[t] += s[t + off];
        __syncthreads();
    }
    if (t == 0) chunkSum[blockIdx.x] = s[0];
}

__global__ __launch_bounds__(256) void scan_chunks_kernel(
    const int* __restrict__ chunkSum, int* __restrict__ chunkOff)
{
    __shared__ int s[256];
    int t = threadIdx.x;
    int v = (t < NC) ? chunkSum[t] : 0;
    s[t] = v;
    __syncthreads();
    for (int off = 1; off < 256; off <<= 1) {
        int u = (t >= off) ? s[t - off] : 0;
        __syncthreads();
        s[t] += u;
        __syncthreads();
    }
    if (t < NC) chunkOff[t] = s[t] - v;
}

__global__ __launch_bounds__(256) void scan_kernel(
    const int* __restrict__ cnt, const int* __restrict__ chunkOff,
    int* __restrict__ offs, int* __restrict__ rowStart)
{
    __shared__ int s[256];
    int t = threadIdx.x;
    int idx = blockIdx.x * 256 + t;
    int v = (idx < NN) ? cnt[idx] : 0;
    s[t] = v;
    __syncthreads();
    for (int off = 1; off < 256; off <<= 1) {
        int u = (t >= off) ? s[t - off] : 0;
        __syncthreads();
        s[t] += u;
        __syncthreads();
    }
    if (idx < NN) {
        int st = chunkOff[blockIdx.x] + s[t] - v;
        offs[idx] = st;
        rowStart[idx] = st;
    }
}

__global__ __launch_bounds__(256) void scatter_idx_kernel(
    const int* __restrict__ ei, int* __restrict__ offs,
    int* __restrict__ sRow, int* __restrict__ sCol)
{
    int e = blockIdx.x * 256 + threadIdx.x;
    if (e < EE) {
        int r = ei[e], c = ei[EE + e];
        int p = atomicAdd(&offs[r], 1);
        sRow[p] = r;
        sCol[p] = c;
    }
}

// ==================== PASS A: edge MLP -> fused scatter-add ===============
constexpr int EPB   = 64;
constexpr int NTILE = EE / EPB;    // 12500
constexpr int XAS   = 264;         // xa stride: 528 B row (33 quads, odd)
constexpr int H1S   = 136;         // h1/msgL stride: 272 B row (17 quads, odd)

__global__ __launch_bounds__(512, 4) void edgeA_kernel(
    const unsigned short* __restrict__ xb, const float* __restrict__ pos,
    const int* __restrict__ sRow, const int* __restrict__ sCol,
    const unsigned short* __restrict__ ew1T, const float* __restrict__ ew1,
    const float* __restrict__ eb1,
    const unsigned short* __restrict__ ew2T, const float* __restrict__ eb2,
    const float* __restrict__ cw,  const float* __restrict__ cb,
    float* __restrict__ agg, float* __restrict__ sSg)
{
    __shared__ float dist2S[EPB];
    __shared__ int   rowS  [EPB];
    __shared__ float sPart[8][EPB];
    __shared__ __align__(16) unsigned short xa  [EPB * XAS];
    __shared__ __align__(16) unsigned short h1  [EPB * H1S];
    __shared__ __align__(16) unsigned short msgL[EPB * H1S];

    const int t   = threadIdx.x;
    const int w   = t >> 6;
    const int l   = t & 63;
    const int l15 = l & 15;
    const int q8  = l >> 4;
    const int n   = w * 16 + l15;

    s16x8 B1[8], B2[4];
    #pragma unroll
    for (int ko = 0; ko < 8; ++ko)
        B1[ko] = *(const s16x8*)(ew1T + (size_t)n * 256 + ko * 32 + q8 * 8);
    #pragma unroll
    for (int ko = 0; ko < 4; ++ko)
        B2[ko] = *(const s16x8*)(ew2T + (size_t)n * 128 + ko * 32 + q8 * 8);
    const float w256 = ew1[256 * FF + n];
    const float b1   = eb1[n];
    const float b2   = eb2[n];
    const float cwc  = cw[n];
    const float cb0  = cb[0];

    const int q   = t & 31;
    const int eB  = t >> 5;
    const int ksel = (q & 15) * 8;
    const int* idxBase = (q < 16) ? sRow : sCol;

    int   nidx[4];
    s16x8 ag[4];
    {
        int e0 = blockIdx.x * EPB;
        #pragma unroll
        for (int i = 0; i < 4; ++i) nidx[i] = idxBase[e0 + eB + 16 * i];
        #pragma unroll
        for (int i = 0; i < 4; ++i) ag[i] = *(const s16x8*)(xb + (size_t)nidx[i] * FF + ksel);
    }

    for (int tile = blockIdx.x; tile < NTILE; tile += gridDim.x) {
        const int e0 = tile * EPB;

        #pragma unroll
        for (int i = 0; i < 4; ++i)
            *(s16x8*)(xa + (eB + 16 * i) * XAS + q * 8) = ag[i];
        if (t < EPB) {
            int r = sRow[e0 + t];
            int c = sCol[e0 + t];
            rowS[t] = r;
            float dx = pos[r*3+0] - pos[c*3+0];
            float dy = pos[r*3+1] - pos[c*3+1];
            float dz = pos[r*3+2] - pos[c*3+2];
            dist2S[t] = dx*dx + dy*dy + dz*dz;
        }
        __syncthreads();   // (A)

        {
            int tn  = tile + gridDim.x;
            int e0n = (tn < NTILE) ? tn * EPB : 0;
            #pragma unroll
            for (int i = 0; i < 4; ++i) nidx[i] = idxBase[e0n + eB + 16 * i];
            #pragma unroll
            for (int i = 0; i < 4; ++i) ag[i] = *(const s16x8*)(xb + (size_t)nidx[i] * FF + ksel);
        }

        f32x4 acc[4] = {};
        #pragma unroll
        for (int mt = 0; mt < 4; ++mt) {
            const unsigned short* ar = xa + (mt * 16 + l15) * XAS + q8 * 8;
            #pragma unroll
            for (int ko = 0; ko < 8; ++ko) {
                s16x8 a = *(const s16x8*)(ar + ko * 32);
                acc[mt] = __builtin_amdgcn_mfma_f32_16x16x32_bf16(a, B1[ko], acc[mt], 0, 0, 0);
            }
        }

        #pragma unroll
        for (int mt = 0; mt < 4; ++mt) {
            #pragma unroll
            for (int r = 0; r < 4; ++r) {
                int e = mt * 16 + q8 * 4 + r;
                float v = acc[mt][r] + dist2S[e] * w256 + b1;
                h1[e * H1S + n] = f2bf(silu_f(v));
            }
        }
        __syncthreads();   // (B)

        f32x4 acc2[4] = {};
        #pragma unroll
        for (int mt = 0; mt < 4; ++mt) {
            const unsigned short* hr = h1 + (mt * 16 + l15) * H1S + q8 * 8;
            #pragma unroll
            for (int ko = 0; ko < 4; ++ko) {
                s16x8 a = *(const s16x8*)(hr + ko * 32);
                acc2[mt] = __builtin_amdgcn_mfma_f32_16x16x32_bf16(a, B2[ko], acc2[mt], 0, 0, 0);
            }
        }

        #pragma unroll
        for (int mt = 0; mt < 4; ++mt) {
            #pragma unroll
            for (int r = 0; r < 4; ++r) {
                float m = acc2[mt][r] + b2;
                float p = m * cwc;
                p += __shfl_xor(p, 1);
                p += __shfl_xor(p, 2);
                p += __shfl_xor(p, 4);
                p += __shfl_xor(p, 8);
                int e = mt * 16 + q8 * 4 + r;
                if (l15 == 0) sPart[w][e] = p;
                msgL[e * H1S + n] = f2bf(m);
            }
        }
        __syncthreads();   // (C)

        if (t < EPB) {
            float p = 0.f;
            #pragma unroll
            for (int ww = 0; ww < 8; ++ww) p += sPart[ww][t];
            sSg[e0 + t] = tanhf(p + cb0);
        }

        // ---- fused segment-reduce + scatter-add into agg ----
        // thread t: column c = t&127, edge-quarter s = t>>7 (16 edges).
        // rows are sorted and wave-uniform (e uniform per wave) -> scalar
        // branch; atomics coalesce (64 lanes -> contiguous addresses).
        {
            int c    = t & 127;
            int s    = t >> 7;
            int base = s * 16;
            float a  = 0.f;
            int cur  = rowS[base];
            #pragma unroll
            for (int k = 0; k < 16; ++k) {
                int e = base + k;
                int r = rowS[e];
                if (r != cur) {
                    atomicAdd(&agg[(size_t)cur * FF + c], a);
                    a = 0.f; cur = r;
                }
                a += bf2f(msgL[e * H1S + c]);
            }
            atomicAdd(&agg[(size_t)cur * FF + c], a);
        }
        __syncthreads();   // (D) protect rowS/msgL from next-tile overwrite
    }
}

// ==================== PASS B: agg read + MFMA node MLP + LN + pos =========
constexpr int NPB = 16;
constexpr int ABS = 136;   // bf16 LDS row stride (272 B, odd quads)

__global__ __launch_bounds__(512) void nodeB_kernel(
    const float* __restrict__ x, const float* __restrict__ pos,
    const float* __restrict__ agg, const float* __restrict__ sSg,
    const int* __restrict__ sCol, const int* __restrict__ rowStart,
    const unsigned short* __restrict__ nw1T, const float* __restrict__ nb1,
    const unsigned short* __restrict__ nw2T, const float* __restrict__ nb2,
    const float* __restrict__ gamma, const float* __restrict__ beta,
    float* __restrict__ xout, float* __restrict__ posout)
{
    __shared__ __align__(16) unsigned short aB [NPB * ABS];
    __shared__ __align__(16) unsigned short h1B[NPB * ABS];
    __shared__ float sRedS[8][NPB];
    __shared__ float sRedQ[8][NPB];
    __shared__ float sPosP[NPB][3][4];

    const int t   = threadIdx.x;
    const int w   = t >> 6;          // 0..7
    const int l   = t & 63;
    const int l15 = l & 15;
    const int q8  = l >> 4;          // 0..3
    const int n0  = blockIdx.x * NPB;
    const int n   = w * 16 + l15;    // this wave's output column

    // ---- load agg rows (f32) -> aB (bf16): 2048 floats, 4 per thread ----
    {
        int idx = t * 4;
        int e = idx >> 7, c = idx & 127;
        float4 v = *(const float4*)&agg[(size_t)(n0 + e) * FF + c];
        u16x4 o;
        o[0] = f2bf(v.x); o[1] = f2bf(v.y); o[2] = f2bf(v.z); o[3] = f2bf(v.w);
        *(u16x4*)(aB + e * ABS + c) = o;
    }

    // ---- pos update: 192 threads, 4-way parallel per (node, dim) ----
    if (t < NPB * 12) {
        int e   = t / 12;
        int rem = t - e * 12;
        int d   = rem % 3;
        int ch  = rem / 3;           // 0..3
        int nn  = n0 + e;
        int p0  = rowStart[nn];
        int p1  = (nn == NN - 1) ? EE : rowStart[nn + 1];
        float pn = pos[nn * 3 + d];
        float sum = 0.f;
        for (int p = p0 + ch; p < p1; p += 4) {
            int c = sCol[p];
            sum += sSg[p] * (pn - pos[c * 3 + d]);
        }
        sPosP[e][d][ch] = sum;
    }
    __syncthreads();

    if (t < NPB * 3) {
        int e = t / 3, d = t % 3;
        int nn = n0 + e;
        posout[nn * 3 + d] = pos[nn * 3 + d]
            + sPosP[e][d][0] + sPosP[e][d][1] + sPosP[e][d][2] + sPosP[e][d][3];
    }

    // ---- GEMM1 (16 nodes x 128 cols, K=128): wave w -> 16 cols ----
    f32x4 acc = {};
    {
        const unsigned short* ar = aB + l15 * ABS + q8 * 8;
        #pragma unroll
        for (int ko = 0; ko < 4; ++ko) {
            s16x8 a = *(const s16x8*)(ar + ko * 32);
            s16x8 b = *(const s16x8*)(nw1T + (size_t)n * 128 + ko * 32 + q8 * 8);
            acc = __builtin_amdgcn_mfma_f32_16x16x32_bf16(a, b, acc, 0, 0, 0);
        }
    }
    {
        float bb = nb1[n];
        #pragma unroll
        for (int r = 0; r < 4; ++r) {
            int e = q8 * 4 + r;
            h1B[e * ABS + n] = f2bf(silu_f(acc[r] + bb));
        }
    }
    __syncthreads();

    // ---- GEMM2 (K=128) ----
    f32x4 acc2 = {};
    {
        const unsigned short* hr = h1B + l15 * ABS + q8 * 8;
        #pragma unroll
        for (int ko = 0; ko < 4; ++ko) {
            s16x8 a = *(const s16x8*)(hr + ko * 32);
            s16x8 b = *(const s16x8*)(nw2T + (size_t)n * 128 + ko * 32 + q8 * 8);
            acc2 = __builtin_amdgcn_mfma_f32_16x16x32_bf16(a, b, acc2, 0, 0, 0);
        }
    }

    // ---- residual + LN ----
    float pre[4];
    {
        float bb = nb2[n];
        #pragma unroll
        for (int r = 0; r < 4; ++r) {
            int e = q8 * 4 + r;
            pre[r] = x[(size_t)(n0 + e) * FF + n] + acc2[r] + bb;
        }
    }
    #pragma unroll
    for (int r = 0; r < 4; ++r) {
        float s = pre[r], sq = pre[r] * pre[r];
        s += __shfl_xor(s, 1);  sq += __shfl_xor(sq, 1);
        s += __shfl_xor(s, 2);  sq += __shfl_xor(sq, 2);
        s += __shfl_xor(s, 4);  sq += __shfl_xor(sq, 4);
        s += __shfl_xor(s, 8);  sq += __shfl_xor(sq, 8);
        if (l15 == 0) {
            int e = q8 * 4 + r;
            sRedS[w][e] = s;
            sRedQ[w][e] = sq;
        }
    }
    __syncthreads();

    {
        float g = gamma[n], bt = beta[n];
        #pragma unroll
        for (int r = 0; r < 4; ++r) {
            int e = q8 * 4 + r;
            float S = 0.f, Q = 0.f;
            #pragma unroll
            for (int ww = 0; ww < 8; ++ww) { S += sRedS[ww][e]; Q += sRedQ[ww][e]; }
            float mean = S * (1.f / FF);
            float var  = Q * (1.f / FF) - mean * mean;
            xout[(size_t)(n0 + e) * FF + n] =
                g * (pre[r] - mean) * rsqrtf(var + LN_EPS) + bt;
        }
    }
}

// -------------------- launcher --------------------
extern "C" void kernel_launch(void* const* d_in, const int* in_sizes, int n_in,
                              void* d_out, int out_size, void* d_ws, size_t ws_size,
                              hipStream_t stream) {
    const float* x    = (const float*)d_in[0];
    const float* pos  = (const float*)d_in[1];
    const int*   ei   = (const int*)  d_in[2];
    const float* ew1  = (const float*)d_in[3];
    const float* eb1  = (const float*)d_in[4];
    const float* ew2  = (const float*)d_in[5];
    const float* eb2  = (const float*)d_in[6];
    const float* nw1  = (const float*)d_in[7];
    const float* nb1  = (const float*)d_in[8];
    const float* nw2  = (const float*)d_in[9];
    const float* nb2  = (const float*)d_in[10];
    const float* cw   = (const float*)d_in[11];
    const float* cb   = (const float*)d_in[12];
    const float* gam  = (const float*)d_in[13];
    const float* bet  = (const float*)d_in[14];

    float* out    = (float*)d_out;
    float* xout   = out;
    float* posout = out + (size_t)NN * FF;

    auto align256 = [](size_t v) { return (v + 255) & ~(size_t)255; };
    char* ws = (char*)d_ws;

    size_t CNT_B   = align256((size_t)NN * 4);
    size_t OFFS_B  = align256((size_t)NN * 4);
    size_t RST_B   = align256((size_t)NN * 4);
    size_t CHNK_B  = align256((size_t)NC * 4 * 2);
    size_t SROW_B  = align256((size_t)EE * 4);
    size_t XB_B    = align256((size_t)NN * FF * 2);
    size_t EW1T_B  = align256((size_t)128 * 256 * 2);
    size_t WT_B    = align256((size_t)128 * 128 * 2);
    size_t AGG_B   = align256((size_t)NN * FF * 4);   // 25.6 MB f32

    size_t o = 0;
    int* cnt       = (int*)(ws + o);  o += CNT_B;    // zeroed
    int* offs      = (int*)(ws + o);  o += OFFS_B;
    int* rowStart  = (int*)(ws + o);  o += RST_B;
    int* chunkSum  = (int*)(ws + o);
    int* chunkOff  = chunkSum + NC;   o += CHNK_B;
    int* sRow      = (int*)(ws + o);  o += SROW_B;
    int* sCol      = (int*)(ws + o);  o += SROW_B;
    unsigned short* xb   = (unsigned short*)(ws + o);  o += XB_B;
    unsigned short* ew1T = (unsigned short*)(ws + o);  o += EW1T_B;
    unsigned short* ew2T = (unsigned short*)(ws + o);  o += WT_B;
    unsigned short* nw1T = (unsigned short*)(ws + o);  o += WT_B;
    unsigned short* nw2T = (unsigned short*)(ws + o);  o += WT_B;
    float*          agg  = (float*)(ws + o);           o += AGG_B;
    float*          sSg  = (float*)(ws + o);

    hipMemsetAsync(cnt, 0, CNT_B, stream);
    hipMemsetAsync(agg, 0, (size_t)NN * FF * 4, stream);

    convert_x_kernel<<<(NN * FF / 8) / 256, 256, 0, stream>>>(x, xb);
    transpose_w_kernel<<<(32768 + 3 * 16384) / 256, 256, 0, stream>>>(
        ew1, ew2, nw1, nw2, ew1T, ew2T, nw1T, nw2T);

    hist_kernel<<<(EE + 255) / 256, 256, 0, stream>>>(ei, cnt);
    chunk_sum_kernel<<<NC, 256, 0, stream>>>(cnt, chunkSum);
    scan_chunks_kernel<<<1, 256, 0, stream>>>(chunkSum, chunkOff);
    scan_kernel<<<NC, 256, 0, stream>>>(cnt, chunkOff, offs, rowStart);
    scatter_idx_kernel<<<(EE + 255) / 256, 256, 0, stream>>>(ei, offs, sRow, sCol);

    edgeA_kernel<<<2048, 512, 0, stream>>>(
        xb, pos, sRow, sCol, ew1T, ew1, eb1, ew2T, eb2, cw, cb, agg, sSg);

    nodeB_kernel<<<NN / NPB, 512, 0, stream>>>(
        x, pos, agg, sSg, sCol, rowStart,
        nw1T, nb1, nw2T, nb2, gam, bet, xout, posout);
}